// Round 8
// baseline (269.156 us; speedup 1.0000x reference)
//
#include <hip/hip_runtime.h>
#include <math.h>

#define TT 2048
#define DD 512
#define HEADS 8
#define DH 64
#define NI 4
#define DI 64
#define KSEL 128

typedef __bf16 bfr;
typedef bfr bf16x8 __attribute__((ext_vector_type(8)));
typedef float f32x4 __attribute__((ext_vector_type(4)));

__device__ __forceinline__ float sigmoidf_(float z) {
    return 1.0f / (1.0f + __expf(-z));
}

__device__ __forceinline__ ushort f2bf(float f) {
    unsigned u = __float_as_uint(f);
    unsigned r = (u + 0x7fffu + ((u >> 16) & 1u)) >> 16;
    return (ushort)r;
}

__device__ __forceinline__ float bf2f(ushort u) {
    return __uint_as_float(((unsigned)u) << 16);
}

// ---------------------------------------------------------------------------
__global__ void castx_kernel(const float* __restrict__ x, ushort* __restrict__ xb) {
    int i = blockIdx.x * blockDim.x + threadIdx.x;
    xb[i] = f2bf(x[i]);
}

// Transpose 6 weight matrices [512][512] fp32 -> WT bf16 [mat*512 + n][k]
__global__ __launch_bounds__(256) void wtrans_kernel(
    const float* __restrict__ W0, const float* __restrict__ W1,
    const float* __restrict__ W2, const float* __restrict__ W3,
    const float* __restrict__ W4, const float* __restrict__ W5,
    ushort* __restrict__ wtb) {
    const float* srcs[6] = {W0, W1, W2, W3, W4, W5};
    const float* W = srcs[blockIdx.z];
    ushort* outp = wtb + (size_t)blockIdx.z * 512 * 512;
    __shared__ float t[32][33];
    int n0 = blockIdx.x * 32, k0 = blockIdx.y * 32;
    int tid = threadIdx.x;
    int c = tid & 31, r8 = tid >> 5;
#pragma unroll
    for (int rr = 0; rr < 32; rr += 8)
        t[r8 + rr][c] = W[(size_t)(k0 + r8 + rr) * 512 + n0 + c];
    __syncthreads();
#pragma unroll
    for (int rr = 0; rr < 32; rr += 8)
        outp[(size_t)(n0 + r8 + rr) * 512 + k0 + c] = f2bf(t[c][r8 + rr]);
}

// ---------------------------------------------------------------------------
// MFMA bf16 GEMM, 128x128 tile, 4 waves, 4x4 16x16x32 tiles per wave.
// Proj routing over {q,k,v,vg,og} by blockIdx.x>>2 (sigmoid epi on vg/og).
// ---------------------------------------------------------------------------
__global__ __launch_bounds__(256) void mfma_gemm(
    const ushort* __restrict__ A, const ushort* __restrict__ BT,
    float* __restrict__ qo, float* __restrict__ ko, float* __restrict__ vo,
    float* __restrict__ vgo, float* __restrict__ ogo,
    const float* __restrict__ bvg, const float* __restrict__ bog) {
    __shared__ __align__(16) ushort As[128][32];
    __shared__ __align__(16) ushort Bs[128][32];
    const int K = 512;
    int tid = threadIdx.x;
    int bm0 = blockIdx.y * 128;
    int bx = blockIdx.x;
    int bn_cat = bx * 128;
    int w = tid >> 6, lane = tid & 63;
    int wm = (w >> 1) * 64, wn = (w & 1) * 64;
    int quad = lane >> 4, mr = lane & 15;
    f32x4 acc[4][4];
#pragma unroll
    for (int i = 0; i < 4; ++i)
#pragma unroll
        for (int j = 0; j < 4; ++j)
#pragma unroll
            for (int r = 0; r < 4; ++r) acc[i][j][r] = 0.f;
    int rs = tid >> 2, cs = (tid & 3) * 8;
    int rs2 = (tid + 256) >> 2;
    for (int k0 = 0; k0 < K; k0 += 32) {
        *(float4*)&As[rs][cs] = *(const float4*)(A + (size_t)(bm0 + rs) * K + k0 + cs);
        *(float4*)&Bs[rs][cs] = *(const float4*)(BT + (size_t)(bn_cat + rs) * K + k0 + cs);
        *(float4*)&As[rs2][cs] = *(const float4*)(A + (size_t)(bm0 + rs2) * K + k0 + cs);
        *(float4*)&Bs[rs2][cs] = *(const float4*)(BT + (size_t)(bn_cat + rs2) * K + k0 + cs);
        __syncthreads();
        bf16x8 af[4], bfv[4];
#pragma unroll
        for (int i = 0; i < 4; ++i)
            af[i] = *(const bf16x8*)&As[wm + i * 16 + mr][quad * 8];
#pragma unroll
        for (int j = 0; j < 4; ++j)
            bfv[j] = *(const bf16x8*)&Bs[wn + j * 16 + mr][quad * 8];
#pragma unroll
        for (int i = 0; i < 4; ++i)
#pragma unroll
            for (int j = 0; j < 4; ++j)
                acc[i][j] = __builtin_amdgcn_mfma_f32_16x16x32_bf16(
                    af[i], bfv[j], acc[i][j], 0, 0, 0);
        __syncthreads();
    }
    int mat = bx >> 2;
    float* C = mat == 0 ? qo : mat == 1 ? ko : mat == 2 ? vo : mat == 3 ? vgo : ogo;
    const float* bias = mat == 3 ? bvg : mat == 4 ? bog : nullptr;
    int bn0 = (bx & 3) * 128;
#pragma unroll
    for (int i = 0; i < 4; ++i)
#pragma unroll
        for (int j = 0; j < 4; ++j) {
            int col = bn0 + wn + j * 16 + mr;
            float bv = bias ? bias[col] : 0.f;
#pragma unroll
            for (int r = 0; r < 4; ++r) {
                int row = bm0 + wm + i * 16 + quad * 4 + r;
                float val = acc[i][j][r];
                if (bias) val = sigmoidf_(val + bv);
                C[(size_t)row * 512 + col] = val;
            }
        }
}

// ---------------------------------------------------------------------------
// Wo MFMA GEMM, 64x64 tile (4 waves x 2x2 fragments) -> 256 blocks.
// ---------------------------------------------------------------------------
__global__ __launch_bounds__(256) void wo64_kernel(
    const ushort* __restrict__ A, const ushort* __restrict__ BT,
    float* __restrict__ C) {
    __shared__ __align__(16) ushort As[64][32];
    __shared__ __align__(16) ushort Bs[64][32];
    const int K = 512;
    int tid = threadIdx.x;
    int bm0 = blockIdx.y * 64, bn0 = blockIdx.x * 64;
    int w = tid >> 6, lane = tid & 63;
    int wm = (w >> 1) * 32, wn = (w & 1) * 32;
    int quad = lane >> 4, mr = lane & 15;
    f32x4 acc[2][2];
#pragma unroll
    for (int i = 0; i < 2; ++i)
#pragma unroll
        for (int j = 0; j < 2; ++j)
#pragma unroll
            for (int r = 0; r < 4; ++r) acc[i][j][r] = 0.f;
    int rs = tid >> 2, cs = (tid & 3) * 8;
    for (int k0 = 0; k0 < K; k0 += 32) {
        *(float4*)&As[rs][cs] = *(const float4*)(A + (size_t)(bm0 + rs) * K + k0 + cs);
        *(float4*)&Bs[rs][cs] = *(const float4*)(BT + (size_t)(bn0 + rs) * K + k0 + cs);
        __syncthreads();
        bf16x8 af[2], bfv[2];
#pragma unroll
        for (int i = 0; i < 2; ++i)
            af[i] = *(const bf16x8*)&As[wm + i * 16 + mr][quad * 8];
#pragma unroll
        for (int j = 0; j < 2; ++j)
            bfv[j] = *(const bf16x8*)&Bs[wn + j * 16 + mr][quad * 8];
#pragma unroll
        for (int i = 0; i < 2; ++i)
#pragma unroll
            for (int j = 0; j < 2; ++j)
                acc[i][j] = __builtin_amdgcn_mfma_f32_16x16x32_bf16(
                    af[i], bfv[j], acc[i][j], 0, 0, 0);
        __syncthreads();
    }
#pragma unroll
    for (int i = 0; i < 2; ++i)
#pragma unroll
        for (int j = 0; j < 2; ++j) {
            int col = bn0 + wn + j * 16 + mr;
#pragma unroll
            for (int r = 0; r < 4; ++r) {
                int row = bm0 + wm + i * 16 + quad * 4 + r;
                C[(size_t)row * 512 + col] = acc[i][j][r];
            }
        }
}

// ---------------------------------------------------------------------------
// fp32 64x64 GEMM tile (exact fp32 score path: Wiq, Wik)
// ---------------------------------------------------------------------------
__device__ __forceinline__ void gemm_tile64(const float* __restrict__ A,
                                            const float* __restrict__ B,
                                            float* __restrict__ C,
                                            int N, int K, int bm, int bn0) {
    __shared__ float Ast[16][64];
    __shared__ float Bs[16][64];
    int tid = threadIdx.x;
    int tx = tid & 15, ty = tid >> 4;
    int ma = tid >> 2, kq = tid & 3;
    int kb_ = tid >> 4, n4 = tid & 15;
    float acc[4][4] = {};
    for (int k0 = 0; k0 < K; k0 += 16) {
        float4 av = *(const float4*)(A + (size_t)(bm + ma) * K + k0 + kq * 4);
        *(float4*)&Bs[kb_][n4 * 4] =
            *(const float4*)(B + (size_t)(k0 + kb_) * N + bn0 + n4 * 4);
        Ast[kq * 4 + 0][ma] = av.x;
        Ast[kq * 4 + 1][ma] = av.y;
        Ast[kq * 4 + 2][ma] = av.z;
        Ast[kq * 4 + 3][ma] = av.w;
        __syncthreads();
#pragma unroll
        for (int kk = 0; kk < 16; ++kk) {
            float4 a4 = *(const float4*)&Ast[kk][ty * 4];
            float4 b4 = *(const float4*)&Bs[kk][tx * 4];
            float af[4] = {a4.x, a4.y, a4.z, a4.w};
            float bf[4] = {b4.x, b4.y, b4.z, b4.w};
#pragma unroll
            for (int i = 0; i < 4; ++i)
#pragma unroll
                for (int j = 0; j < 4; ++j) acc[i][j] += af[i] * bf[j];
        }
        __syncthreads();
    }
#pragma unroll
    for (int i = 0; i < 4; ++i) {
        int mrow = bm + ty * 4 + i;
#pragma unroll
        for (int j = 0; j < 4; ++j)
            C[(size_t)mrow * N + bn0 + tx * 4 + j] = acc[i][j];
    }
}

__global__ __launch_bounds__(256) void proj32_kernel(
    const float* __restrict__ x, const float* __restrict__ Wiq,
    const float* __restrict__ Wik, float* __restrict__ qib,
    float* __restrict__ kib) {
    int bn = blockIdx.x, bm = blockIdx.y * 64;
    if (bn < 4)
        gemm_tile64(x, Wiq, qib, 256, 512, bm, bn * 64);
    else
        gemm_tile64(x, Wik, kib, 64, 512, bm, 0);
}

__global__ __launch_bounds__(256) void iw_kernel(const float* __restrict__ x,
                                                 const float* __restrict__ Wiw,
                                                 const float* __restrict__ biw,
                                                 float* __restrict__ wsig) {
    int t = blockIdx.x;
    int tid = threadIdx.x;
    int lane = tid & 63, c = tid >> 6;
    float acc = 0.f;
    for (int k = lane; k < DD; k += 64) acc += x[t * DD + k] * Wiw[k * NI + c];
#pragma unroll
    for (int off = 32; off; off >>= 1) acc += __shfl_down(acc, off);
    if (lane == 0) wsig[t * NI + c] = sigmoidf_(acc + biw[c]);
}

// v_bf16 = bf16(v * vg)
__global__ void vmul_kernel(const float* __restrict__ v,
                            const float* __restrict__ vg,
                            ushort* __restrict__ v16) {
    int i = blockIdx.x * blockDim.x + threadIdx.x;
    v16[i] = f2bf(v[i] * vg[i]);
}

// RoPE: q updated in place (fp32); k emitted as bf16 only.
__global__ void rope_kernel(float* __restrict__ q, const float* __restrict__ k,
                            ushort* __restrict__ k16) {
    int i = blockIdx.x * blockDim.x + threadIdx.x;
    int j = i & 31;
    int h = (i >> 5) & 7;
    int t = i >> 8;
    if (t >= TT) return;
    const float L2_10000 = 13.287712379549449f;
    float inv = exp2f(-(float)j * (1.0f / 32.0f) * L2_10000);
    float ang = (float)t * inv;
    float c = cosf(ang), s = sinf(ang);
    int base = t * DD + h * DH;
    float q1 = q[base + j], q2 = q[base + j + 32];
    q[base + j] = q1 * c - q2 * s;
    q[base + j + 32] = q2 * c + q1 * s;
    float k1 = k[base + j], k2 = k[base + j + 32];
    k16[base + j] = f2bf(k1 * c - k2 * s);
    k16[base + j + 32] = f2bf(k2 * c + k1 * s);
}

// ---------------------------------------------------------------------------
// Index-score GEMM over lower-triangle 64x64 tiles -> monotone uint keys.
// ---------------------------------------------------------------------------
__global__ __launch_bounds__(256) void score_kernel(
    const float* __restrict__ qi, const float* __restrict__ ki,
    const float* __restrict__ wsig, const float* __restrict__ idx_bias,
    unsigned* __restrict__ keys) {
    __shared__ float As[64][65];
    __shared__ float Bs[64][65];
    int b = blockIdx.x;
    int bq = (int)((sqrtf(8.0f * (float)b + 1.0f) - 1.0f) * 0.5f);
    while ((bq + 1) * (bq + 2) / 2 <= b) ++bq;
    while (bq * (bq + 1) / 2 > b) --bq;
    int bk = b - bq * (bq + 1) / 2;
    int q0 = bq * 64, k0 = bk * 64;
    int tid = threadIdx.x;
    int tx = tid & 15, ty = tid >> 4;
    float fin[4][4] = {};
#pragma unroll
    for (int h = 0; h < NI; ++h) {
#pragma unroll
        for (int i = 0; i < 4; ++i) {
            int e = tid + i * 256;
            int r = e >> 4, c4 = e & 15;
            float4 av = *(const float4*)(qi + (size_t)(q0 + r) * (NI * DI) + h * DI + c4 * 4);
            As[r][c4 * 4 + 0] = av.x;
            As[r][c4 * 4 + 1] = av.y;
            As[r][c4 * 4 + 2] = av.z;
            As[r][c4 * 4 + 3] = av.w;
            float4 bv = *(const float4*)(ki + (size_t)(k0 + r) * DI + c4 * 4);
            Bs[c4 * 4 + 0][r] = bv.x;
            Bs[c4 * 4 + 1][r] = bv.y;
            Bs[c4 * 4 + 2][r] = bv.z;
            Bs[c4 * 4 + 3][r] = bv.w;
        }
        __syncthreads();
        float raw[4][4] = {};
#pragma unroll 8
        for (int kk = 0; kk < 64; ++kk) {
            float a[4], bb[4];
#pragma unroll
            for (int i = 0; i < 4; ++i) a[i] = As[ty * 4 + i][kk];
#pragma unroll
            for (int j = 0; j < 4; ++j) bb[j] = Bs[kk][tx * 4 + j];
#pragma unroll
            for (int i = 0; i < 4; ++i)
#pragma unroll
                for (int j = 0; j < 4; ++j) raw[i][j] += a[i] * bb[j];
        }
        float bh = idx_bias[h];
        float w4[4];
#pragma unroll
        for (int i = 0; i < 4; ++i) w4[i] = wsig[(q0 + ty * 4 + i) * NI + h];
#pragma unroll
        for (int i = 0; i < 4; ++i)
#pragma unroll
            for (int j = 0; j < 4; ++j)
                fin[i][j] += sigmoidf_(raw[i][j] * 0.125f + bh) * w4[i];
        __syncthreads();
    }
#pragma unroll
    for (int i = 0; i < 4; ++i) {
        int qq = q0 + ty * 4 + i;
#pragma unroll
        for (int j = 0; j < 4; ++j) {
            int kk = k0 + tx * 4 + j;
            unsigned key = 0;
            if (kk <= qq) {
                unsigned u = __float_as_uint(fin[i][j]);
                key = (u & 0x80000000u) ? ~u : (u | 0x80000000u);
            }
            keys[(size_t)qq * TT + kk] = key;
        }
    }
}

// ---------------------------------------------------------------------------
// Exact per-row top-K via MSB-first radix select. Ties -> lowest index.
// ---------------------------------------------------------------------------
__global__ __launch_bounds__(256) void topk_kernel(
    const unsigned* __restrict__ keys, int* __restrict__ indices,
    int* __restrict__ counts) {
    __shared__ unsigned ks_[TT];
    __shared__ unsigned hist[256];
    __shared__ unsigned wtot[4];
    __shared__ unsigned s_prefix, s_above;
    __shared__ int eqlist[256];
    __shared__ unsigned eqcount, outpos;
    int qrow = blockIdx.x;
    int tid = threadIdx.x;
    int lane = tid & 63, wv = tid >> 6;
    int n = qrow + 1;
    if (n <= KSEL) {
        if (tid < n) indices[qrow * KSEL + tid] = tid;
        if (tid == 0) counts[qrow] = n;
        return;
    }
    if (tid == 0) counts[qrow] = KSEL;
    const unsigned* krow = keys + (size_t)qrow * TT;
    for (int k = tid; k < n; k += 256) ks_[k] = krow[k];
    __syncthreads();
    unsigned prefix = 0;
    int remaining = KSEL;
    for (int level = 24; level >= 0; level -= 8) {
        hist[tid] = 0;
        __syncthreads();
        for (int k = tid; k < n; k += 256) {
            unsigned key = ks_[k];
            bool match = ((unsigned long long)key >> (level + 8)) == (unsigned long long)prefix;
            if (match) atomicAdd(&hist[(key >> level) & 255], 1u);
        }
        __syncthreads();
        unsigned v = hist[tid];
#pragma unroll
        for (int off = 1; off < 64; off <<= 1) {
            unsigned t = __shfl_down(v, off);
            if (lane + off < 64) v += t;
        }
        if (lane == 0) wtot[wv] = v;
        __syncthreads();
        unsigned add = 0;
#pragma unroll
        for (int u = 1; u < 4; ++u)
            if (wv + u < 4) add += wtot[wv + u];
        v += add;
        hist[tid] = v;
        __syncthreads();
        if (hist[tid] >= (unsigned)remaining &&
            (tid == 255 || hist[tid + 1] < (unsigned)remaining)) {
            s_prefix = (prefix << 8) | (unsigned)tid;
            s_above = (tid == 255) ? 0u : hist[tid + 1];
        }
        __syncthreads();
        prefix = s_prefix;
        remaining -= (int)s_above;
        __syncthreads();
    }
    if (tid == 0) { eqcount = 0; outpos = 0; }
    __syncthreads();
    int outbase = qrow * KSEL;
    for (int k = tid; k < n; k += 256) {
        unsigned key = ks_[k];
        if (key > prefix) {
            unsigned p = atomicAdd(&outpos, 1u);
            indices[outbase + p] = k;
        } else if (key == prefix) {
            unsigned e = atomicAdd(&eqcount, 1u);
            if (e < 256) eqlist[e] = k;
        }
    }
    __syncthreads();
    if (tid == 0) {
        int r = remaining;
        int E = (int)eqcount;
        if (E > 256) E = 256;
        if (r > E) r = E;
        int pos = (int)outpos;
        for (int t = 0; t < r; ++t) {
            int best = 0x7fffffff, bj = -1;
            for (int j = 0; j < E; ++j) {
                int vv = eqlist[j];
                if (vv < best) { best = vv; bj = j; }
            }
            eqlist[bj] = 0x7fffffff;
            indices[outbase + pos + t] = best;
        }
    }
}

// ---------------------------------------------------------------------------
// Sparse attention: grid (TT, 2); wave w handles head blockIdx.y*4 + w.
// QK: 16-lane groups read K rows direct from global, shuffle-reduce dots.
// No K staging in LDS; LDS = idx + per-wave p only (~2.5 KB).
// ---------------------------------------------------------------------------
__global__ __launch_bounds__(256) void attn_kernel(
    const float* __restrict__ q, const ushort* __restrict__ k16,
    const ushort* __restrict__ v16, const float* __restrict__ og,
    const int* __restrict__ indices, const int* __restrict__ counts,
    ushort* __restrict__ out) {
    __shared__ int idx[KSEL];
    __shared__ float pw[4][KSEL];
    int qrow = blockIdx.x;
    int tid = threadIdx.x;
    int lane = tid & 63, w = tid >> 6;
    int cnt = counts[qrow];
    if (tid < KSEL) idx[tid] = (tid < cnt) ? indices[qrow * KSEL + tid] : 0;
    __syncthreads();
    float* ppw = pw[w];
    int h = blockIdx.y * 4 + w;
    int hb = h * DH;
    int g16 = lane & 15, r4 = lane >> 4;
    int cs = g16 * 4;
    float4 qd = *(const float4*)(q + (size_t)qrow * DD + hb + cs);
    // --- QK dots: 4 rows per iteration, 16 lanes per row
#pragma unroll 8
    for (int it = 0; it < 32; ++it) {
        int r = it * 4 + r4;
        int row = idx[r];
        uint2 kv = *(const uint2*)(k16 + (size_t)row * DD + hb + cs);
        float f0 = __uint_as_float(kv.x << 16);
        float f1 = __uint_as_float(kv.x & 0xffff0000u);
        float f2 = __uint_as_float(kv.y << 16);
        float f3 = __uint_as_float(kv.y & 0xffff0000u);
        float part = f0 * qd.x + f1 * qd.y + f2 * qd.z + f3 * qd.w;
#pragma unroll
        for (int off = 1; off < 16; off <<= 1) part += __shfl_xor(part, off);
        if (g16 == 0) ppw[r] = part;
    }
    // --- softmax over 128 (2 keys per lane)
    float d0 = (lane < cnt) ? ppw[lane] * 0.125f : -1e30f;
    float d1 = (lane + 64 < cnt) ? ppw[lane + 64] * 0.125f : -1e30f;
    float m = fmaxf(d0, d1);
#pragma unroll
    for (int off = 1; off < 64; off <<= 1) m = fmaxf(m, __shfl_xor(m, off));
    float p0 = __expf(d0 - m), p1 = __expf(d1 - m);
    float sum = p0 + p1;
#pragma unroll
    for (int off = 1; off < 64; off <<= 1) sum += __shfl_xor(sum, off);
    float inv = 1.0f / sum;
    ppw[lane] = p0 * inv;
    ppw[lane + 64] = p1 * inv;
    // --- PV: lane covers d = dp*2+{0,1}; halves split keys
    int dp = lane & 31, half = lane >> 5;
    float2 a0 = {0.f, 0.f}, a1 = {0.f, 0.f};
#pragma unroll 8
    for (int t = 0; t < 64; t += 2) {
        int jA = 2 * t + half;
        int jB = 2 * t + 2 + half;
        int rowA = idx[jA];
        int rowB = idx[jB];
        float pA = ppw[jA], pB = ppw[jB];
        unsigned va = *(const unsigned*)(v16 + (size_t)rowA * DD + hb + dp * 2);
        unsigned vb = *(const unsigned*)(v16 + (size_t)rowB * DD + hb + dp * 2);
        a0.x += pA * __uint_as_float(va << 16);
        a0.y += pA * __uint_as_float(va & 0xffff0000u);
        a1.x += pB * __uint_as_float(vb << 16);
        a1.y += pB * __uint_as_float(vb & 0xffff0000u);
    }
    float ax = a0.x + a1.x, ay = a0.y + a1.y;
    ax += __shfl_xor(ax, 32);
    ay += __shfl_xor(ay, 32);
    if (half == 0) {
        int o = qrow * DD + hb + dp * 2;
        float2 g = *(const float2*)(og + o);
        ushort2 r;
        r.x = f2bf(ax * g.x);
        r.y = f2bf(ay * g.y);
        *(ushort2*)(out + o) = r;
    }
}

// ---------------------------------------------------------------------------
extern "C" void kernel_launch(void* const* d_in, const int* in_sizes, int n_in,
                              void* d_out, int out_size, void* d_ws, size_t ws_size,
                              hipStream_t stream) {
    const float* x = (const float*)d_in[0];
    const float* Wq = (const float*)d_in[1];
    const float* Wk = (const float*)d_in[2];
    const float* Wv = (const float*)d_in[3];
    const float* Wo = (const float*)d_in[4];
    const float* Wiq = (const float*)d_in[5];
    const float* Wik = (const float*)d_in[6];
    const float* Wiw = (const float*)d_in[7];
    const float* biw = (const float*)d_in[8];
    const float* idx_bias = (const float*)d_in[9];
    const float* Wvg = (const float*)d_in[10];
    const float* bvg = (const float*)d_in[11];
    const float* Wog = (const float*)d_in[12];
    const float* bog = (const float*)d_in[13];
    float* out = (float*)d_out;
    char* base = (char*)d_ws;

    float* qb = (float*)(base + 0);
    float* kb = (float*)(base + (4ull << 20));
    float* vb = (float*)(base + (8ull << 20));
    float* vgb = (float*)(base + (12ull << 20));
    float* ogb = (float*)(base + (16ull << 20));
    float* qib = (float*)(base + (20ull << 20));
    float* kib = (float*)(base + (22ull << 20));
    float* wsb = (float*)(base + (22ull << 20) + (512u << 10));
    ushort* xb = (ushort*)(base + (23ull << 20));
    ushort* wtb = (ushort*)(base + (25ull << 20));
    ushort* kb16 = (ushort*)(base + (28ull << 20));
    ushort* vb16 = (ushort*)(base + (30ull << 20));
    unsigned* keysb = (unsigned*)(base + (32ull << 20));
    ushort* ab_bf = (ushort*)(base + (32ull << 20));
    int* idxb = (int*)(base + (12ull << 20));
    int* cntb = (int*)(base + (13ull << 20) + (512u << 10));

    dim3 blk(256);
    castx_kernel<<<TT * DD / 256, blk, 0, stream>>>(x, xb);
    wtrans_kernel<<<dim3(16, 16, 6), blk, 0, stream>>>(Wq, Wk, Wv, Wvg, Wog, Wo, wtb);
    proj32_kernel<<<dim3(5, 32), blk, 0, stream>>>(x, Wiq, Wik, qib, kib);
    iw_kernel<<<TT, blk, 0, stream>>>(x, Wiw, biw, wsb);
    mfma_gemm<<<dim3(20, 16), blk, 0, stream>>>(xb, wtb, qb, kb, vb, vgb, ogb,
                                                bvg, bog);
    vmul_kernel<<<(TT * DD) / 256, blk, 0, stream>>>(vb, vgb, vb16);
    rope_kernel<<<(TT * HEADS * 32) / 256, blk, 0, stream>>>(qb, kb, kb16);
    score_kernel<<<528, blk, 0, stream>>>(qib, kib, wsb, idx_bias, keysb);
    topk_kernel<<<TT, blk, 0, stream>>>(keysb, idxb, cntb);
    attn_kernel<<<dim3(TT, 2), blk, 0, stream>>>(qb, kb16, vb16, ogb, idxb, cntb, ab_bf);
    wo64_kernel<<<dim3(8, 32), blk, 0, stream>>>(ab_bf, wtb + (size_t)5 * 512 * 512, out);
}

// Round 9
// 261.400 us; speedup vs baseline: 1.0297x; 1.0297x over previous
//
#include <hip/hip_runtime.h>
#include <math.h>

#define TT 2048
#define DD 512
#define HEADS 8
#define DH 64
#define NI 4
#define DI 64
#define KSEL 128

typedef __bf16 bfr;
typedef bfr bf16x8 __attribute__((ext_vector_type(8)));
typedef float f32x4 __attribute__((ext_vector_type(4)));

__device__ __forceinline__ float sigmoidf_(float z) {
    return 1.0f / (1.0f + __expf(-z));
}

__device__ __forceinline__ ushort f2bf(float f) {
    unsigned u = __float_as_uint(f);
    unsigned r = (u + 0x7fffu + ((u >> 16) & 1u)) >> 16;
    return (ushort)r;
}

__device__ __forceinline__ float bf2f(ushort u) {
    return __uint_as_float(((unsigned)u) << 16);
}

// ---------------------------------------------------------------------------
__global__ void castx_kernel(const float* __restrict__ x, ushort* __restrict__ xb) {
    int i = blockIdx.x * blockDim.x + threadIdx.x;
    xb[i] = f2bf(x[i]);
}

// Transpose 6 weight matrices [512][512] fp32 -> WT bf16 [mat*512 + n][k]
__global__ __launch_bounds__(256) void wtrans_kernel(
    const float* __restrict__ W0, const float* __restrict__ W1,
    const float* __restrict__ W2, const float* __restrict__ W3,
    const float* __restrict__ W4, const float* __restrict__ W5,
    ushort* __restrict__ wtb) {
    const float* srcs[6] = {W0, W1, W2, W3, W4, W5};
    const float* W = srcs[blockIdx.z];
    ushort* outp = wtb + (size_t)blockIdx.z * 512 * 512;
    __shared__ float t[32][33];
    int n0 = blockIdx.x * 32, k0 = blockIdx.y * 32;
    int tid = threadIdx.x;
    int c = tid & 31, r8 = tid >> 5;
#pragma unroll
    for (int rr = 0; rr < 32; rr += 8)
        t[r8 + rr][c] = W[(size_t)(k0 + r8 + rr) * 512 + n0 + c];
    __syncthreads();
#pragma unroll
    for (int rr = 0; rr < 32; rr += 8)
        outp[(size_t)(n0 + r8 + rr) * 512 + k0 + c] = f2bf(t[c][r8 + rr]);
}

// ---------------------------------------------------------------------------
// MFMA bf16 GEMM, 128x128 tile, 4 waves, 4x4 16x16x32 tiles per wave.
// Proj routing over {q,k,v,vg,og} by blockIdx.x>>2 (sigmoid epi on vg/og).
// ---------------------------------------------------------------------------
__global__ __launch_bounds__(256) void mfma_gemm(
    const ushort* __restrict__ A, const ushort* __restrict__ BT,
    float* __restrict__ qo, float* __restrict__ ko, float* __restrict__ vo,
    float* __restrict__ vgo, float* __restrict__ ogo,
    const float* __restrict__ bvg, const float* __restrict__ bog) {
    __shared__ __align__(16) ushort As[128][32];
    __shared__ __align__(16) ushort Bs[128][32];
    const int K = 512;
    int tid = threadIdx.x;
    int bm0 = blockIdx.y * 128;
    int bx = blockIdx.x;
    int bn_cat = bx * 128;
    int w = tid >> 6, lane = tid & 63;
    int wm = (w >> 1) * 64, wn = (w & 1) * 64;
    int quad = lane >> 4, mr = lane & 15;
    f32x4 acc[4][4];
#pragma unroll
    for (int i = 0; i < 4; ++i)
#pragma unroll
        for (int j = 0; j < 4; ++j)
#pragma unroll
            for (int r = 0; r < 4; ++r) acc[i][j][r] = 0.f;
    int rs = tid >> 2, cs = (tid & 3) * 8;
    int rs2 = (tid + 256) >> 2;
    for (int k0 = 0; k0 < K; k0 += 32) {
        *(float4*)&As[rs][cs] = *(const float4*)(A + (size_t)(bm0 + rs) * K + k0 + cs);
        *(float4*)&Bs[rs][cs] = *(const float4*)(BT + (size_t)(bn_cat + rs) * K + k0 + cs);
        *(float4*)&As[rs2][cs] = *(const float4*)(A + (size_t)(bm0 + rs2) * K + k0 + cs);
        *(float4*)&Bs[rs2][cs] = *(const float4*)(BT + (size_t)(bn_cat + rs2) * K + k0 + cs);
        __syncthreads();
        bf16x8 af[4], bfv[4];
#pragma unroll
        for (int i = 0; i < 4; ++i)
            af[i] = *(const bf16x8*)&As[wm + i * 16 + mr][quad * 8];
#pragma unroll
        for (int j = 0; j < 4; ++j)
            bfv[j] = *(const bf16x8*)&Bs[wn + j * 16 + mr][quad * 8];
#pragma unroll
        for (int i = 0; i < 4; ++i)
#pragma unroll
            for (int j = 0; j < 4; ++j)
                acc[i][j] = __builtin_amdgcn_mfma_f32_16x16x32_bf16(
                    af[i], bfv[j], acc[i][j], 0, 0, 0);
        __syncthreads();
    }
    int mat = bx >> 2;
    float* C = mat == 0 ? qo : mat == 1 ? ko : mat == 2 ? vo : mat == 3 ? vgo : ogo;
    const float* bias = mat == 3 ? bvg : mat == 4 ? bog : nullptr;
    int bn0 = (bx & 3) * 128;
#pragma unroll
    for (int i = 0; i < 4; ++i)
#pragma unroll
        for (int j = 0; j < 4; ++j) {
            int col = bn0 + wn + j * 16 + mr;
            float bv = bias ? bias[col] : 0.f;
#pragma unroll
            for (int r = 0; r < 4; ++r) {
                int row = bm0 + wm + i * 16 + quad * 4 + r;
                float val = acc[i][j][r];
                if (bias) val = sigmoidf_(val + bv);
                C[(size_t)row * 512 + col] = val;
            }
        }
}

// ---------------------------------------------------------------------------
// Wo MFMA GEMM, 64x64 tile (4 waves x 2x2 fragments) -> 256 blocks.
// ---------------------------------------------------------------------------
__global__ __launch_bounds__(256) void wo64_kernel(
    const ushort* __restrict__ A, const ushort* __restrict__ BT,
    float* __restrict__ C) {
    __shared__ __align__(16) ushort As[64][32];
    __shared__ __align__(16) ushort Bs[64][32];
    const int K = 512;
    int tid = threadIdx.x;
    int bm0 = blockIdx.y * 64, bn0 = blockIdx.x * 64;
    int w = tid >> 6, lane = tid & 63;
    int wm = (w >> 1) * 32, wn = (w & 1) * 32;
    int quad = lane >> 4, mr = lane & 15;
    f32x4 acc[2][2];
#pragma unroll
    for (int i = 0; i < 2; ++i)
#pragma unroll
        for (int j = 0; j < 2; ++j)
#pragma unroll
            for (int r = 0; r < 4; ++r) acc[i][j][r] = 0.f;
    int rs = tid >> 2, cs = (tid & 3) * 8;
    for (int k0 = 0; k0 < K; k0 += 32) {
        *(float4*)&As[rs][cs] = *(const float4*)(A + (size_t)(bm0 + rs) * K + k0 + cs);
        *(float4*)&Bs[rs][cs] = *(const float4*)(BT + (size_t)(bn0 + rs) * K + k0 + cs);
        __syncthreads();
        bf16x8 af[2], bfv[2];
#pragma unroll
        for (int i = 0; i < 2; ++i)
            af[i] = *(const bf16x8*)&As[wm + i * 16 + mr][quad * 8];
#pragma unroll
        for (int j = 0; j < 2; ++j)
            bfv[j] = *(const bf16x8*)&Bs[wn + j * 16 + mr][quad * 8];
#pragma unroll
        for (int i = 0; i < 2; ++i)
#pragma unroll
            for (int j = 0; j < 2; ++j)
                acc[i][j] = __builtin_amdgcn_mfma_f32_16x16x32_bf16(
                    af[i], bfv[j], acc[i][j], 0, 0, 0);
        __syncthreads();
    }
#pragma unroll
    for (int i = 0; i < 2; ++i)
#pragma unroll
        for (int j = 0; j < 2; ++j) {
            int col = bn0 + wn + j * 16 + mr;
#pragma unroll
            for (int r = 0; r < 4; ++r) {
                int row = bm0 + wm + i * 16 + quad * 4 + r;
                C[(size_t)row * 512 + col] = acc[i][j][r];
            }
        }
}

// ---------------------------------------------------------------------------
// fp32 64x64 GEMM tile (exact fp32 score path: Wiq, Wik)
// ---------------------------------------------------------------------------
__device__ __forceinline__ void gemm_tile64(const float* __restrict__ A,
                                            const float* __restrict__ B,
                                            float* __restrict__ C,
                                            int N, int K, int bm, int bn0) {
    __shared__ float Ast[16][64];
    __shared__ float Bs[16][64];
    int tid = threadIdx.x;
    int tx = tid & 15, ty = tid >> 4;
    int ma = tid >> 2, kq = tid & 3;
    int kb_ = tid >> 4, n4 = tid & 15;
    float acc[4][4] = {};
    for (int k0 = 0; k0 < K; k0 += 16) {
        float4 av = *(const float4*)(A + (size_t)(bm + ma) * K + k0 + kq * 4);
        *(float4*)&Bs[kb_][n4 * 4] =
            *(const float4*)(B + (size_t)(k0 + kb_) * N + bn0 + n4 * 4);
        Ast[kq * 4 + 0][ma] = av.x;
        Ast[kq * 4 + 1][ma] = av.y;
        Ast[kq * 4 + 2][ma] = av.z;
        Ast[kq * 4 + 3][ma] = av.w;
        __syncthreads();
#pragma unroll
        for (int kk = 0; kk < 16; ++kk) {
            float4 a4 = *(const float4*)&Ast[kk][ty * 4];
            float4 b4 = *(const float4*)&Bs[kk][tx * 4];
            float af[4] = {a4.x, a4.y, a4.z, a4.w};
            float bf[4] = {b4.x, b4.y, b4.z, b4.w};
#pragma unroll
            for (int i = 0; i < 4; ++i)
#pragma unroll
                for (int j = 0; j < 4; ++j) acc[i][j] += af[i] * bf[j];
        }
        __syncthreads();
    }
#pragma unroll
    for (int i = 0; i < 4; ++i) {
        int mrow = bm + ty * 4 + i;
#pragma unroll
        for (int j = 0; j < 4; ++j)
            C[(size_t)mrow * N + bn0 + tx * 4 + j] = acc[i][j];
    }
}

__global__ __launch_bounds__(256) void proj32_kernel(
    const float* __restrict__ x, const float* __restrict__ Wiq,
    const float* __restrict__ Wik, float* __restrict__ qib,
    float* __restrict__ kib) {
    int bn = blockIdx.x, bm = blockIdx.y * 64;
    if (bn < 4)
        gemm_tile64(x, Wiq, qib, 256, 512, bm, bn * 64);
    else
        gemm_tile64(x, Wik, kib, 64, 512, bm, 0);
}

__global__ __launch_bounds__(256) void iw_kernel(const float* __restrict__ x,
                                                 const float* __restrict__ Wiw,
                                                 const float* __restrict__ biw,
                                                 float* __restrict__ wsig) {
    int t = blockIdx.x;
    int tid = threadIdx.x;
    int lane = tid & 63, c = tid >> 6;
    float acc = 0.f;
    for (int k = lane; k < DD; k += 64) acc += x[t * DD + k] * Wiw[k * NI + c];
#pragma unroll
    for (int off = 32; off; off >>= 1) acc += __shfl_down(acc, off);
    if (lane == 0) wsig[t * NI + c] = sigmoidf_(acc + biw[c]);
}

// v_bf16 = bf16(v * vg)
__global__ void vmul_kernel(const float* __restrict__ v,
                            const float* __restrict__ vg,
                            ushort* __restrict__ v16) {
    int i = blockIdx.x * blockDim.x + threadIdx.x;
    v16[i] = f2bf(v[i] * vg[i]);
}

// RoPE: q updated in place (fp32); k emitted as bf16 only.
__global__ void rope_kernel(float* __restrict__ q, const float* __restrict__ k,
                            ushort* __restrict__ k16) {
    int i = blockIdx.x * blockDim.x + threadIdx.x;
    int j = i & 31;
    int h = (i >> 5) & 7;
    int t = i >> 8;
    if (t >= TT) return;
    const float L2_10000 = 13.287712379549449f;
    float inv = exp2f(-(float)j * (1.0f / 32.0f) * L2_10000);
    float ang = (float)t * inv;
    float c = cosf(ang), s = sinf(ang);
    int base = t * DD + h * DH;
    float q1 = q[base + j], q2 = q[base + j + 32];
    q[base + j] = q1 * c - q2 * s;
    q[base + j + 32] = q2 * c + q1 * s;
    float k1 = k[base + j], k2 = k[base + j + 32];
    k16[base + j] = f2bf(k1 * c - k2 * s);
    k16[base + j + 32] = f2bf(k2 * c + k1 * s);
}

// ---------------------------------------------------------------------------
// Index-score GEMM over lower-triangle 64x64 tiles -> monotone uint keys.
// Bs (ki tile) staged ONCE; As re-staged per head.
// ---------------------------------------------------------------------------
__global__ __launch_bounds__(256) void score_kernel(
    const float* __restrict__ qi, const float* __restrict__ ki,
    const float* __restrict__ wsig, const float* __restrict__ idx_bias,
    unsigned* __restrict__ keys) {
    __shared__ float As[64][65];
    __shared__ float Bs[64][65];
    int b = blockIdx.x;
    int bq = (int)((sqrtf(8.0f * (float)b + 1.0f) - 1.0f) * 0.5f);
    while ((bq + 1) * (bq + 2) / 2 <= b) ++bq;
    while (bq * (bq + 1) / 2 > b) --bq;
    int bk = b - bq * (bq + 1) / 2;
    int q0 = bq * 64, k0 = bk * 64;
    int tid = threadIdx.x;
    int tx = tid & 15, ty = tid >> 4;
    float fin[4][4] = {};
    // stage Bs once (transposed ki tile) + As for head 0
#pragma unroll
    for (int i = 0; i < 4; ++i) {
        int e = tid + i * 256;
        int r = e >> 4, c4 = e & 15;
        float4 bv = *(const float4*)(ki + (size_t)(k0 + r) * DI + c4 * 4);
        Bs[c4 * 4 + 0][r] = bv.x;
        Bs[c4 * 4 + 1][r] = bv.y;
        Bs[c4 * 4 + 2][r] = bv.z;
        Bs[c4 * 4 + 3][r] = bv.w;
        float4 av = *(const float4*)(qi + (size_t)(q0 + r) * (NI * DI) + c4 * 4);
        As[r][c4 * 4 + 0] = av.x;
        As[r][c4 * 4 + 1] = av.y;
        As[r][c4 * 4 + 2] = av.z;
        As[r][c4 * 4 + 3] = av.w;
    }
    __syncthreads();
#pragma unroll
    for (int h = 0; h < NI; ++h) {
        float raw[4][4] = {};
#pragma unroll 8
        for (int kk = 0; kk < 64; ++kk) {
            float a[4], bb[4];
#pragma unroll
            for (int i = 0; i < 4; ++i) a[i] = As[ty * 4 + i][kk];
#pragma unroll
            for (int j = 0; j < 4; ++j) bb[j] = Bs[kk][tx * 4 + j];
#pragma unroll
            for (int i = 0; i < 4; ++i)
#pragma unroll
                for (int j = 0; j < 4; ++j) raw[i][j] += a[i] * bb[j];
        }
        float bh = idx_bias[h];
        float w4[4];
#pragma unroll
        for (int i = 0; i < 4; ++i) w4[i] = wsig[(q0 + ty * 4 + i) * NI + h];
#pragma unroll
        for (int i = 0; i < 4; ++i)
#pragma unroll
            for (int j = 0; j < 4; ++j)
                fin[i][j] += sigmoidf_(raw[i][j] * 0.125f + bh) * w4[i];
        if (h < NI - 1) {
            __syncthreads();
#pragma unroll
            for (int i = 0; i < 4; ++i) {
                int e = tid + i * 256;
                int r = e >> 4, c4 = e & 15;
                float4 av = *(const float4*)(qi + (size_t)(q0 + r) * (NI * DI) +
                                             (h + 1) * DI + c4 * 4);
                As[r][c4 * 4 + 0] = av.x;
                As[r][c4 * 4 + 1] = av.y;
                As[r][c4 * 4 + 2] = av.z;
                As[r][c4 * 4 + 3] = av.w;
            }
            __syncthreads();
        }
    }
#pragma unroll
    for (int i = 0; i < 4; ++i) {
        int qq = q0 + ty * 4 + i;
#pragma unroll
        for (int j = 0; j < 4; ++j) {
            int kk = k0 + tx * 4 + j;
            unsigned key = 0;
            if (kk <= qq) {
                unsigned u = __float_as_uint(fin[i][j]);
                key = (u & 0x80000000u) ? ~u : (u | 0x80000000u);
            }
            keys[(size_t)qq * TT + kk] = key;
        }
    }
}

// ---------------------------------------------------------------------------
// Exact per-row top-K via MSB-first radix select. Ties -> lowest index.
// ---------------------------------------------------------------------------
__global__ __launch_bounds__(256) void topk_kernel(
    const unsigned* __restrict__ keys, int* __restrict__ indices,
    int* __restrict__ counts) {
    __shared__ unsigned ks_[TT];
    __shared__ unsigned hist[256];
    __shared__ unsigned wtot[4];
    __shared__ unsigned s_prefix, s_above;
    __shared__ int eqlist[256];
    __shared__ unsigned eqcount, outpos;
    int qrow = blockIdx.x;
    int tid = threadIdx.x;
    int lane = tid & 63, wv = tid >> 6;
    int n = qrow + 1;
    if (n <= KSEL) {
        if (tid < n) indices[qrow * KSEL + tid] = tid;
        if (tid == 0) counts[qrow] = n;
        return;
    }
    if (tid == 0) counts[qrow] = KSEL;
    const unsigned* krow = keys + (size_t)qrow * TT;
    for (int k = tid; k < n; k += 256) ks_[k] = krow[k];
    __syncthreads();
    unsigned prefix = 0;
    int remaining = KSEL;
    for (int level = 24; level >= 0; level -= 8) {
        hist[tid] = 0;
        __syncthreads();
        for (int k = tid; k < n; k += 256) {
            unsigned key = ks_[k];
            bool match = ((unsigned long long)key >> (level + 8)) == (unsigned long long)prefix;
            if (match) atomicAdd(&hist[(key >> level) & 255], 1u);
        }
        __syncthreads();
        unsigned v = hist[tid];
#pragma unroll
        for (int off = 1; off < 64; off <<= 1) {
            unsigned t = __shfl_down(v, off);
            if (lane + off < 64) v += t;
        }
        if (lane == 0) wtot[wv] = v;
        __syncthreads();
        unsigned add = 0;
#pragma unroll
        for (int u = 1; u < 4; ++u)
            if (wv + u < 4) add += wtot[wv + u];
        v += add;
        hist[tid] = v;
        __syncthreads();
        if (hist[tid] >= (unsigned)remaining &&
            (tid == 255 || hist[tid + 1] < (unsigned)remaining)) {
            s_prefix = (prefix << 8) | (unsigned)tid;
            s_above = (tid == 255) ? 0u : hist[tid + 1];
        }
        __syncthreads();
        prefix = s_prefix;
        remaining -= (int)s_above;
        __syncthreads();
    }
    if (tid == 0) { eqcount = 0; outpos = 0; }
    __syncthreads();
    int outbase = qrow * KSEL;
    for (int k = tid; k < n; k += 256) {
        unsigned key = ks_[k];
        if (key > prefix) {
            unsigned p = atomicAdd(&outpos, 1u);
            indices[outbase + p] = k;
        } else if (key == prefix) {
            unsigned e = atomicAdd(&eqcount, 1u);
            if (e < 256) eqlist[e] = k;
        }
    }
    __syncthreads();
    if (tid == 0) {
        int r = remaining;
        int E = (int)eqcount;
        if (E > 256) E = 256;
        if (r > E) r = E;
        int pos = (int)outpos;
        for (int t = 0; t < r; ++t) {
            int best = 0x7fffffff, bj = -1;
            for (int j = 0; j < E; ++j) {
                int vv = eqlist[j];
                if (vv < best) { best = vv; bj = j; }
            }
            eqlist[bj] = 0x7fffffff;
            indices[outbase + pos + t] = best;
        }
    }
}

// ---------------------------------------------------------------------------
// Sparse attention: grid (TT,2), wave w owns head blockIdx.y*4+w.
// QK: K chunks staged in per-wave LDS, per-lane serial dots (R7 structure).
// PV: lane owns a d-quad (ushort4), keys quarter-split over 16-lane groups.
// ---------------------------------------------------------------------------
__global__ __launch_bounds__(256) void attn_kernel(
    const float* __restrict__ q, const ushort* __restrict__ k16,
    const ushort* __restrict__ v16, const float* __restrict__ og,
    const int* __restrict__ indices, const int* __restrict__ counts,
    ushort* __restrict__ out) {
    __shared__ int idx[KSEL];
    __shared__ ushort kw[4][32 * 68];
    __shared__ float qv[4][DH];
    __shared__ float pw[4][KSEL];
    int qrow = blockIdx.x;
    int tid = threadIdx.x;
    int lane = tid & 63, w = tid >> 6;
    int cnt = counts[qrow];
    if (tid < KSEL) idx[tid] = (tid < cnt) ? indices[qrow * KSEL + tid] : 0;
    __syncthreads();
    ushort* kws = kw[w];
    float* qvs = qv[w];
    float* pps = pw[w];
    int h = blockIdx.y * 4 + w;
    int hb = h * DH;
    qvs[lane] = q[qrow * DD + hb + lane];
    int j2 = lane & 31, half = lane >> 5;
    int r4 = lane >> 4, cs = (lane & 15) * 4;
    float sc[4];
#pragma unroll
    for (int c = 0; c < 4; ++c) {
#pragma unroll
        for (int it = 0; it < 8; ++it) {
            int r = it * 4 + r4;
            int row = idx[c * 32 + r];
            *(ushort4*)&kws[r * 68 + cs] =
                *(const ushort4*)(k16 + (size_t)row * DD + hb + cs);
        }
        float acc0 = 0.f, acc1 = 0.f;
        const ushort* kr = kws + j2 * 68 + half * 32;
        const float* qr = qvs + half * 32;
#pragma unroll
        for (int dd = 0; dd < 8; dd += 2) {
            ushort4 ka = *(const ushort4*)&kr[dd * 4];
            ushort4 kb_ = *(const ushort4*)&kr[dd * 4 + 4];
            acc0 += bf2f(ka.x) * qr[dd * 4 + 0] + bf2f(ka.y) * qr[dd * 4 + 1] +
                    bf2f(ka.z) * qr[dd * 4 + 2] + bf2f(ka.w) * qr[dd * 4 + 3];
            acc1 += bf2f(kb_.x) * qr[dd * 4 + 4] + bf2f(kb_.y) * qr[dd * 4 + 5] +
                    bf2f(kb_.z) * qr[dd * 4 + 6] + bf2f(kb_.w) * qr[dd * 4 + 7];
        }
        float acc = acc0 + acc1;
        acc += __shfl_xor(acc, 32);
        int j = c * 32 + j2;
        sc[c] = (j < cnt) ? acc * 0.125f : -1e30f;
    }
    // wave-local softmax (halves mirrored)
    float m = fmaxf(fmaxf(sc[0], sc[1]), fmaxf(sc[2], sc[3]));
#pragma unroll
    for (int off = 16; off; off >>= 1) m = fmaxf(m, __shfl_xor(m, off));
    float pc[4], sum = 0.f;
#pragma unroll
    for (int c = 0; c < 4; ++c) {
        pc[c] = __expf(sc[c] - m);
        sum += pc[c];
    }
#pragma unroll
    for (int off = 16; off; off >>= 1) sum += __shfl_xor(sum, off);
    float inv = 1.0f / sum;
    if (half == 0) {
#pragma unroll
        for (int c = 0; c < 4; ++c) pps[c * 32 + j2] = pc[c] * inv;
    }
    // PV: lane -> d-quad dgroup*4, key quarter g; 8 independent fma chains
    int dgroup = lane & 15, g = lane >> 4;
    int db = dgroup * 4;
    float a0 = 0.f, a1 = 0.f, a2 = 0.f, a3 = 0.f;
    float b0 = 0.f, b1 = 0.f, b2 = 0.f, b3 = 0.f;
#pragma unroll 8
    for (int t = 0; t < 32; t += 2) {
        int jA = g + 4 * t;
        int jB = g + 4 * t + 4;
        int rowA = idx[jA];
        int rowB = idx[jB];
        float pA = pps[jA], pB = pps[jB];
        ushort4 va = *(const ushort4*)(v16 + (size_t)rowA * DD + hb + db);
        ushort4 vb = *(const ushort4*)(v16 + (size_t)rowB * DD + hb + db);
        a0 += pA * bf2f(va.x); a1 += pA * bf2f(va.y);
        a2 += pA * bf2f(va.z); a3 += pA * bf2f(va.w);
        b0 += pB * bf2f(vb.x); b1 += pB * bf2f(vb.y);
        b2 += pB * bf2f(vb.z); b3 += pB * bf2f(vb.w);
    }
    a0 += b0; a1 += b1; a2 += b2; a3 += b3;
    a0 += __shfl_xor(a0, 16); a0 += __shfl_xor(a0, 32);
    a1 += __shfl_xor(a1, 16); a1 += __shfl_xor(a1, 32);
    a2 += __shfl_xor(a2, 16); a2 += __shfl_xor(a2, 32);
    a3 += __shfl_xor(a3, 16); a3 += __shfl_xor(a3, 32);
    if (g == 0) {
        int o = qrow * DD + hb + db;
        float4 gg = *(const float4*)(og + o);
        ushort4 r;
        r.x = f2bf(a0 * gg.x);
        r.y = f2bf(a1 * gg.y);
        r.z = f2bf(a2 * gg.z);
        r.w = f2bf(a3 * gg.w);
        *(ushort4*)(out + o) = r;
    }
}

// ---------------------------------------------------------------------------
extern "C" void kernel_launch(void* const* d_in, const int* in_sizes, int n_in,
                              void* d_out, int out_size, void* d_ws, size_t ws_size,
                              hipStream_t stream) {
    const float* x = (const float*)d_in[0];
    const float* Wq = (const float*)d_in[1];
    const float* Wk = (const float*)d_in[2];
    const float* Wv = (const float*)d_in[3];
    const float* Wo = (const float*)d_in[4];
    const float* Wiq = (const float*)d_in[5];
    const float* Wik = (const float*)d_in[6];
    const float* Wiw = (const float*)d_in[7];
    const float* biw = (const float*)d_in[8];
    const float* idx_bias = (const float*)d_in[9];
    const float* Wvg = (const float*)d_in[10];
    const float* bvg = (const float*)d_in[11];
    const float* Wog = (const float*)d_in[12];
    const float* bog = (const float*)d_in[13];
    float* out = (float*)d_out;
    char* base = (char*)d_ws;

    float* qb = (float*)(base + 0);
    float* kb = (float*)(base + (4ull << 20));
    float* vb = (float*)(base + (8ull << 20));
    float* vgb = (float*)(base + (12ull << 20));
    float* ogb = (float*)(base + (16ull << 20));
    float* qib = (float*)(base + (20ull << 20));
    float* kib = (float*)(base + (22ull << 20));
    float* wsb = (float*)(base + (22ull << 20) + (512u << 10));
    ushort* xb = (ushort*)(base + (23ull << 20));
    ushort* wtb = (ushort*)(base + (25ull << 20));
    ushort* kb16 = (ushort*)(base + (28ull << 20));
    ushort* vb16 = (ushort*)(base + (30ull << 20));
    unsigned* keysb = (unsigned*)(base + (32ull << 20));
    ushort* ab_bf = (ushort*)(base + (32ull << 20));
    int* idxb = (int*)(base + (12ull << 20));
    int* cntb = (int*)(base + (13ull << 20) + (512u << 10));

    dim3 blk(256);
    castx_kernel<<<TT * DD / 256, blk, 0, stream>>>(x, xb);
    wtrans_kernel<<<dim3(16, 16, 6), blk, 0, stream>>>(Wq, Wk, Wv, Wvg, Wog, Wo, wtb);
    proj32_kernel<<<dim3(5, 32), blk, 0, stream>>>(x, Wiq, Wik, qib, kib);
    iw_kernel<<<TT, blk, 0, stream>>>(x, Wiw, biw, wsb);
    mfma_gemm<<<dim3(20, 16), blk, 0, stream>>>(xb, wtb, qb, kb, vb, vgb, ogb,
                                                bvg, bog);
    vmul_kernel<<<(TT * DD) / 256, blk, 0, stream>>>(vb, vgb, vb16);
    rope_kernel<<<(TT * HEADS * 32) / 256, blk, 0, stream>>>(qb, kb, kb16);
    score_kernel<<<528, blk, 0, stream>>>(qib, kib, wsb, idx_bias, keysb);
    topk_kernel<<<TT, blk, 0, stream>>>(keysb, idxb, cntb);
    attn_kernel<<<dim3(TT, 2), blk, 0, stream>>>(qb, kb16, vb16, ogb, idxb, cntb, ab_bf);
    wo64_kernel<<<dim3(8, 32), blk, 0, stream>>>(ab_bf, wtb + (size_t)5 * 512 * 512, out);
}